// Round 1
// baseline (1333.685 us; speedup 1.0000x reference)
//
#include <hip/hip_runtime.h>
#include <hip/hip_bf16.h>

#define N_NODES 100000
#define N_EDGES 3200000
#define IN_DIM  256
#define OUT_DIM 64

// ---------------------------------------------------------------------------
// Kernel 1: detect edge_index dtype. If data is int64 (little-endian, values
// < 2^31), every odd 32-bit word is 0. If int32, odd words are random node
// ids (nonzero w.h.p. across 500K+ samples). Writes flag=1 if any nonzero.
// ---------------------------------------------------------------------------
__global__ void detect_dtype_kernel(const int* __restrict__ ei32, int* __restrict__ flag, int nwords) {
    int i = blockIdx.x * blockDim.x + threadIdx.x;
    int stride = blockDim.x * gridDim.x;
    int found = 0;
    for (int w = 2 * i + 1; w < nwords; w += 2 * stride)
        found |= (ei32[w] != 0);
    if (found) atomicOr(flag, 1);
}

__device__ __forceinline__ void load_edge(const void* ei, int e, bool is64, int& s, int& d) {
    if (is64) {
        const long long* e64 = (const long long*)ei;
        s = (int)e64[e];
        d = (int)e64[N_EDGES + e];
    } else {
        const int* e32 = (const int*)ei;
        s = e32[e];
        d = e32[N_EDGES + e];
    }
}

// ---------------------------------------------------------------------------
// Kernel 2: degree count on destination (edges only; +1 self-loop added later)
// ---------------------------------------------------------------------------
__global__ void degree_kernel(const void* __restrict__ ei, const int* __restrict__ flag,
                              int* __restrict__ deg) {
    bool is64 = (*flag == 0);
    int i = blockIdx.x * blockDim.x + threadIdx.x;
    int stride = blockDim.x * gridDim.x;
    for (int e = i; e < N_EDGES; e += stride) {
        int s, d;
        load_edge(ei, e, is64, s, d);
        atomicAdd(&deg[d], 1);
    }
}

// ---------------------------------------------------------------------------
// Kernel 3: single-block exclusive scan over degrees -> CSR offsets + cursor
// copy; also deg_isqrt / deg_inv (with +1 self-loop).
// ---------------------------------------------------------------------------
__global__ __launch_bounds__(1024) void scan_kernel(const int* __restrict__ deg,
                                                    int* __restrict__ offs,
                                                    int* __restrict__ cursor,
                                                    float* __restrict__ isq,
                                                    float* __restrict__ dinv) {
    __shared__ int part[1024];
    const int n = N_NODES;
    int tid = threadIdx.x;
    int chunk = (n + 1023) >> 10;            // 98
    int b = tid * chunk;
    int e = b + chunk; if (e > n) e = n;
    if (b > n) b = n;

    int s = 0;
    for (int i = b; i < e; ++i) s += deg[i];

    int val = s;
    part[tid] = val;
    __syncthreads();
    for (int off = 1; off < 1024; off <<= 1) {
        int t = (tid >= off) ? part[tid - off] : 0;
        __syncthreads();
        val += t;
        part[tid] = val;
        __syncthreads();
    }
    int run = val - s;                        // exclusive prefix for this chunk
    for (int i = b; i < e; ++i) {
        offs[i] = run;
        cursor[i] = run;
        int dg = deg[i];
        run += dg;
        float dr = (float)(dg + 1);
        isq[i] = rsqrtf(dr);
        dinv[i] = 1.0f / dr;
    }
    if (e == n) offs[n] = run;                // == N_EDGES (consistent for all writers)
}

// ---------------------------------------------------------------------------
// Kernel 4: CSR fill (src index + precomputed edge norm), grouped by dst.
// ---------------------------------------------------------------------------
__global__ void fill_kernel(const void* __restrict__ ei, const int* __restrict__ flag,
                            int* __restrict__ cursor, const float* __restrict__ isq,
                            int* __restrict__ csr_src, float* __restrict__ csr_nrm) {
    bool is64 = (*flag == 0);
    int i = blockIdx.x * blockDim.x + threadIdx.x;
    int stride = blockDim.x * gridDim.x;
    for (int e = i; e < N_EDGES; e += stride) {
        int s, d;
        load_edge(ei, e, is64, s, d);
        int pos = atomicAdd(&cursor[d], 1);
        csr_src[pos] = s;
        csr_nrm[pos] = isq[s] * isq[d];
    }
}

// ---------------------------------------------------------------------------
// Kernel 5: fused f32 GEMM: h[node][0:64]=x@W_hp+b, [64:128]=x@W_lp+b,
// [128:192]=x@W_i+b. Block: 64 nodes x 192 outs, 256 threads (4x12 per thread).
// ---------------------------------------------------------------------------
__global__ __launch_bounds__(256) void gemm_kernel(
    const float* __restrict__ x,
    const float* __restrict__ Whp, const float* __restrict__ bhp,
    const float* __restrict__ Wlp, const float* __restrict__ blp,
    const float* __restrict__ Wi,  const float* __restrict__ bi,
    float* __restrict__ h) {
    __shared__ float xs[64][65];
    __shared__ float ws[64][192];
    const int n = N_NODES;
    int tid = threadIdx.x;
    int node0 = blockIdx.x * 64;
    int ty = tid >> 4, tx = tid & 15;

    float acc[4][12];
    #pragma unroll
    for (int i = 0; i < 4; ++i)
        #pragma unroll
        for (int j = 0; j < 12; ++j) acc[i][j] = 0.f;

    for (int kt = 0; kt < IN_DIM; kt += 64) {
        for (int idx = tid; idx < 64 * 64; idx += 256) {
            int r = idx >> 6, c = idx & 63;
            int node = node0 + r;
            xs[r][c] = (node < n) ? x[(size_t)node * IN_DIM + kt + c] : 0.f;
        }
        for (int idx = tid; idx < 64 * 192; idx += 256) {
            int r = idx / 192, c = idx % 192;
            int k = kt + r;
            float w;
            if (c < 64)       w = Whp[k * 64 + c];
            else if (c < 128) w = Wlp[k * 64 + (c - 64)];
            else              w = Wi [k * 64 + (c - 128)];
            ws[r][c] = w;
        }
        __syncthreads();
        #pragma unroll 8
        for (int k = 0; k < 64; ++k) {
            float a[4], bv[12];
            #pragma unroll
            for (int i = 0; i < 4; ++i) a[i] = xs[ty * 4 + i][k];
            #pragma unroll
            for (int j = 0; j < 12; ++j) bv[j] = ws[k][tx * 12 + j];
            #pragma unroll
            for (int i = 0; i < 4; ++i)
                #pragma unroll
                for (int j = 0; j < 12; ++j)
                    acc[i][j] = fmaf(a[i], bv[j], acc[i][j]);
        }
        __syncthreads();
    }
    #pragma unroll
    for (int i = 0; i < 4; ++i) {
        int node = node0 + ty * 4 + i;
        if (node >= n) continue;
        #pragma unroll
        for (int j = 0; j < 12; ++j) {
            int c = tx * 12 + j;
            float bsum = (c < 64) ? bhp[c] : (c < 128) ? blp[c - 64] : bi[c - 128];
            h[(size_t)node * 192 + c] = acc[i][j] + bsum;
        }
    }
}

// ---------------------------------------------------------------------------
// Kernel 6: fused aggregation + gates + log_softmax. One wave (64 lanes) per
// node; lane = feature dim. Gathers h[src] rows (2 coalesced 256B loads per
// neighbor), accumulates agg_hp/agg_lp in registers, then full epilogue.
// ---------------------------------------------------------------------------
__device__ __forceinline__ float wave_sum(float x) {
    #pragma unroll
    for (int off = 32; off > 0; off >>= 1) x += __shfl_xor(x, off);
    return x;
}
__device__ __forceinline__ float wave_max(float x) {
    #pragma unroll
    for (int off = 32; off > 0; off >>= 1) x = fmaxf(x, __shfl_xor(x, off));
    return x;
}

__global__ __launch_bounds__(256) void agg_kernel(
    const float* __restrict__ h,
    const int* __restrict__ offs,
    const int* __restrict__ csr_src, const float* __restrict__ csr_nrm,
    const float* __restrict__ dinv,
    const float* __restrict__ w_gh, const float* __restrict__ b_gh,
    const float* __restrict__ w_gl, const float* __restrict__ b_gl,
    const float* __restrict__ w_gi, const float* __restrict__ b_gi,
    float* __restrict__ out) {
    int v = blockIdx.x * 4 + (threadIdx.x >> 6);
    int lane = threadIdx.x & 63;
    if (v >= N_NODES) return;

    int start = offs[v], end = offs[v + 1];
    float acc_hp = 0.f, acc_lp = 0.f;

    for (int j0 = start; j0 < end; j0 += 64) {
        int m = end - j0; if (m > 64) m = 64;
        int uu = 0; float nn = 0.f;
        if (lane < m) { uu = csr_src[j0 + lane]; nn = csr_nrm[j0 + lane]; }
        for (int k = 0; k < m; ++k) {
            int u = __shfl(uu, k);
            float nrm = __shfl(nn, k);
            const float* hu = h + (size_t)u * 192;
            acc_hp = fmaf(nrm, hu[lane], acc_hp);
            acc_lp = fmaf(nrm, hu[64 + lane], acc_lp);
        }
    }

    const float* hv = h + (size_t)v * 192;
    float hhp = hv[lane], hlp = hv[64 + lane], hi = hv[128 + lane];
    float dv = dinv[v];
    float Hhp = fmaxf(hhp - (acc_hp + dv * hhp), 0.f);
    float Hlp = fmaxf(acc_lp + dv * hlp, 0.f);
    float Hi  = fmaxf(hi, 0.f);

    float sh = wave_sum(Hhp * w_gh[lane]) + b_gh[0];
    float sl = wave_sum(Hlp * w_gl[lane]) + b_gl[0];
    float si = wave_sum(Hi  * w_gi[lane]) + b_gi[0];

    float o = sh * Hhp + sl * Hlp + si * Hi;
    float mx = wave_max(o);
    float se = wave_sum(expf(o - mx));
    out[(size_t)v * 64 + lane] = o - mx - logf(se);
}

// ---------------------------------------------------------------------------
extern "C" void kernel_launch(void* const* d_in, const int* in_sizes, int n_in,
                              void* d_out, int out_size, void* d_ws, size_t ws_size,
                              hipStream_t stream) {
    const float* x    = (const float*)d_in[0];
    const void*  ei   = d_in[1];
    const float* Whp  = (const float*)d_in[2];
    const float* bhp  = (const float*)d_in[3];
    const float* Wlp  = (const float*)d_in[4];
    const float* blp  = (const float*)d_in[5];
    const float* Wi   = (const float*)d_in[6];
    const float* bi   = (const float*)d_in[7];
    const float* w_gh = (const float*)d_in[8];
    const float* b_gh = (const float*)d_in[9];
    const float* w_gl = (const float*)d_in[10];
    const float* b_gl = (const float*)d_in[11];
    const float* w_gi = (const float*)d_in[12];
    const float* b_gi = (const float*)d_in[13];
    float* out = (float*)d_out;

    const int N = N_NODES, E = N_EDGES;

    // workspace layout
    char* w = (char*)d_ws;
    int*   flag    = (int*)w;                        // [1]  (padded to 256B)
    int*   deg     = (int*)(w + 256);                // [N]
    int*   offs    = deg + N;                        // [N+1]
    int*   cursor  = offs + (N + 1);                 // [N]
    float* isq     = (float*)(cursor + N);           // [N]
    float* dinv    = isq + N;                        // [N]
    int*   csr_src = (int*)(dinv + N);               // [E]
    float* csr_nrm = (float*)(csr_src + E);          // [E]
    float* h       = csr_nrm + E;                    // [N*192]

    // zero flag + deg
    hipMemsetAsync(w, 0, 256 + (size_t)N * sizeof(int), stream);

    detect_dtype_kernel<<<256, 256, 0, stream>>>((const int*)ei, flag, 2 * E);
    degree_kernel<<<2048, 256, 0, stream>>>(ei, flag, deg);
    scan_kernel<<<1, 1024, 0, stream>>>(deg, offs, cursor, isq, dinv);
    fill_kernel<<<2048, 256, 0, stream>>>(ei, flag, cursor, isq, csr_src, csr_nrm);
    gemm_kernel<<<(N + 63) / 64, 256, 0, stream>>>(x, Whp, bhp, Wlp, blp, Wi, bi, h);
    agg_kernel<<<(N + 3) / 4, 256, 0, stream>>>(h, offs, csr_src, csr_nrm, dinv,
                                                w_gh, b_gh, w_gl, b_gl, w_gi, b_gi, out);
}

// Round 2
// 964.009 us; speedup vs baseline: 1.3835x; 1.3835x over previous
//
#include <hip/hip_runtime.h>
#include <hip/hip_bf16.h>

#define N_NODES 100000
#define N_EDGES 3200000
#define IN_DIM  256
#define OUT_DIM 64

typedef __attribute__((ext_vector_type(8))) short short8;
typedef __attribute__((ext_vector_type(4))) float float4v;

// ---------------------------------------------------------------------------
// Kernel 1: detect edge_index dtype. int64 (values < 2^31) -> every odd 32-bit
// word is 0. int32 -> odd words are node ids (nonzero w.h.p.). flag=1 -> int32.
// ---------------------------------------------------------------------------
__global__ void detect_dtype_kernel(const int* __restrict__ ei32, int* __restrict__ flag, int nwords) {
    int i = blockIdx.x * blockDim.x + threadIdx.x;
    int stride = blockDim.x * gridDim.x;
    int found = 0;
    for (int w = 2 * i + 1; w < nwords; w += 2 * stride)
        found |= (ei32[w] != 0);
    if (found) atomicOr(flag, 1);
}

__device__ __forceinline__ void load_edge(const void* ei, int e, bool is64, int& s, int& d) {
    if (is64) {
        const long long* e64 = (const long long*)ei;
        s = (int)e64[e];
        d = (int)e64[N_EDGES + e];
    } else {
        const int* e32 = (const int*)ei;
        s = e32[e];
        d = e32[N_EDGES + e];
    }
}

// ---------------------------------------------------------------------------
// Kernel 2: degree count on destination
// ---------------------------------------------------------------------------
__global__ void degree_kernel(const void* __restrict__ ei, const int* __restrict__ flag,
                              int* __restrict__ deg) {
    bool is64 = (*flag == 0);
    int i = blockIdx.x * blockDim.x + threadIdx.x;
    int stride = blockDim.x * gridDim.x;
    for (int e = i; e < N_EDGES; e += stride) {
        int s, d;
        load_edge(ei, e, is64, s, d);
        atomicAdd(&deg[d], 1);
    }
}

// ---------------------------------------------------------------------------
// Kernel 3: single-block scan -> CSR offsets, cursors, deg_isqrt, deg_inv
// ---------------------------------------------------------------------------
__global__ __launch_bounds__(1024) void scan_kernel(const int* __restrict__ deg,
                                                    int* __restrict__ offs,
                                                    int* __restrict__ cursor,
                                                    float* __restrict__ isq,
                                                    float* __restrict__ dinv) {
    __shared__ int part[1024];
    const int n = N_NODES;
    int tid = threadIdx.x;
    int chunk = (n + 1023) >> 10;
    int b = tid * chunk;
    int e = b + chunk; if (e > n) e = n;
    if (b > n) b = n;

    int s = 0;
    for (int i = b; i < e; ++i) s += deg[i];

    int val = s;
    part[tid] = val;
    __syncthreads();
    for (int off = 1; off < 1024; off <<= 1) {
        int t = (tid >= off) ? part[tid - off] : 0;
        __syncthreads();
        val += t;
        part[tid] = val;
        __syncthreads();
    }
    int run = val - s;
    for (int i = b; i < e; ++i) {
        offs[i] = run;
        cursor[i] = run;
        int dg = deg[i];
        run += dg;
        float dr = (float)(dg + 1);
        isq[i] = rsqrtf(dr);
        dinv[i] = 1.0f / dr;
    }
    if (e == n) offs[n] = run;
}

// ---------------------------------------------------------------------------
// Kernel 4: CSR fill (src + edge norm), grouped by dst
// ---------------------------------------------------------------------------
__global__ void fill_kernel(const void* __restrict__ ei, const int* __restrict__ flag,
                            int* __restrict__ cursor, const float* __restrict__ isq,
                            int* __restrict__ csr_src, float* __restrict__ csr_nrm) {
    bool is64 = (*flag == 0);
    int i = blockIdx.x * blockDim.x + threadIdx.x;
    int stride = blockDim.x * gridDim.x;
    for (int e = i; e < N_EDGES; e += stride) {
        int s, d;
        load_edge(ei, e, is64, s, d);
        int pos = atomicAdd(&cursor[d], 1);
        csr_src[pos] = s;
        csr_nrm[pos] = isq[s] * isq[d];
    }
}

// ---------------------------------------------------------------------------
// Kernel 5: prep weights: Wt[c][k] = bf16(W[k][c]) for c in [0,192), plus
// fused bias vector biasAll[192].
// ---------------------------------------------------------------------------
__global__ void prep_w_kernel(const float* __restrict__ Whp, const float* __restrict__ bhp,
                              const float* __restrict__ Wlp, const float* __restrict__ blp,
                              const float* __restrict__ Wi,  const float* __restrict__ bi,
                              __hip_bfloat16* __restrict__ Wt, float* __restrict__ biasAll) {
    int c = blockIdx.x;      // 0..191
    int k = threadIdx.x;     // 0..255
    const float* W = (c < 64) ? Whp : (c < 128) ? Wlp : Wi;
    int cl = c & 63;
    Wt[c * 256 + k] = __float2bfloat16(W[k * 64 + cl]);
    if (k == 0) {
        const float* b = (c < 64) ? bhp : (c < 128) ? blp : bi;
        biasAll[c] = b[cl];
    }
}

// ---------------------------------------------------------------------------
// Kernel 6: bf16 MFMA GEMM. Block = 256 threads (4 waves), 64 nodes.
// Wave w owns col tiles {w, w+4, w+8} = cols {16w..16w+15} of hp, lp, i —
// so each lane holds the (hp,lp) pair for its column and can emit the packed
// bf16x2 gather table directly.
// B-fragments (all of W for this wave's cols) held in registers (24 frags).
// x tile staged full-K in LDS as bf16, row-padded to 264 (2-way-free reads).
// ---------------------------------------------------------------------------
__global__ __launch_bounds__(256) void gemm_kernel(
    const float* __restrict__ x,
    const __hip_bfloat16* __restrict__ Wt,
    const float* __restrict__ biasAll,
    float* __restrict__ h, unsigned int* __restrict__ hg) {

    __shared__ __align__(16) __hip_bfloat16 xs[64][264];

    const int tid = threadIdx.x;
    const int node0 = blockIdx.x * 64;
    const int w = tid >> 6;
    const int lane = tid & 63;
    const int cl = lane & 15;
    const int kh = lane >> 4;

    // --- B fragments: Wt[col][ks*32 + kh*8 .. +8], col = 16w + 64s + cl ---
    short8 B[3][8];
    #pragma unroll
    for (int s = 0; s < 3; ++s) {
        const __hip_bfloat16* wp = Wt + (16 * w + 64 * s + cl) * 256 + kh * 8;
        #pragma unroll
        for (int ks = 0; ks < 8; ++ks)
            B[s][ks] = *(const short8*)(wp + ks * 32);
    }

    // --- stage x tile (64 x 256 f32 -> bf16 LDS), coalesced 16B/lane ---
    #pragma unroll
    for (int j = 0; j < 16; ++j) {
        int f = j * 1024 + tid * 4;          // flat float index in tile
        int rr = f >> 8, cc = f & 255;
        float4v v = {0.f, 0.f, 0.f, 0.f};
        int node = node0 + rr;
        if (node < N_NODES)
            v = *(const float4v*)(x + (size_t)node * 256 + cc);
        __hip_bfloat16 b0 = __float2bfloat16(v.x), b1 = __float2bfloat16(v.y);
        __hip_bfloat16 b2 = __float2bfloat16(v.z), b3 = __float2bfloat16(v.w);
        unsigned int lo = (unsigned int)*(unsigned short*)&b0 | ((unsigned int)*(unsigned short*)&b1 << 16);
        unsigned int hi = (unsigned int)*(unsigned short*)&b2 | ((unsigned int)*(unsigned short*)&b3 << 16);
        unsigned int* dst = (unsigned int*)&xs[rr][cc];
        dst[0] = lo; dst[1] = hi;
    }
    __syncthreads();

    // --- MFMA main loop: 8 k-steps x (4 row tiles x 3 col slots) ---
    float4v acc[4][3];
    #pragma unroll
    for (int rt = 0; rt < 4; ++rt)
        #pragma unroll
        for (int s = 0; s < 3; ++s)
            acc[rt][s] = (float4v){0.f, 0.f, 0.f, 0.f};

    const char* xbase = (const char*)&xs[0][0];
    #pragma unroll
    for (int ks = 0; ks < 8; ++ks) {
        short8 A[4];
        #pragma unroll
        for (int rt = 0; rt < 4; ++rt)
            A[rt] = *(const short8*)(xbase + (size_t)(rt * 16 + cl) * 528 + ks * 64 + kh * 16);
        #pragma unroll
        for (int rt = 0; rt < 4; ++rt)
            #pragma unroll
            for (int s = 0; s < 3; ++s)
                acc[rt][s] = __builtin_amdgcn_mfma_f32_16x16x32_bf16(A[rt], B[s][ks], acc[rt][s], 0, 0, 0);
    }

    // --- epilogue: bias + store h (f32) + packed bf16x2 gather table ---
    const int c0 = 16 * w + cl;
    const float bias_hp = biasAll[c0];
    const float bias_lp = biasAll[c0 + 64];
    const float bias_i  = biasAll[c0 + 128];

    #pragma unroll
    for (int rt = 0; rt < 4; ++rt) {
        #pragma unroll
        for (int r = 0; r < 4; ++r) {
            int node = node0 + rt * 16 + kh * 4 + r;
            if (node >= N_NODES) continue;
            float vhp = acc[rt][0][r] + bias_hp;
            float vlp = acc[rt][1][r] + bias_lp;
            float vi  = acc[rt][2][r] + bias_i;
            float* hrow = h + (size_t)node * 192;
            hrow[c0]       = vhp;
            hrow[c0 + 64]  = vlp;
            hrow[c0 + 128] = vi;
            __hip_bfloat16 bh = __float2bfloat16(vhp);
            __hip_bfloat16 bl = __float2bfloat16(vlp);
            hg[(size_t)node * 64 + c0] =
                (unsigned int)*(unsigned short*)&bh | ((unsigned int)*(unsigned short*)&bl << 16);
        }
    }
}

// ---------------------------------------------------------------------------
// Kernel 7: fused aggregation + gates + log_softmax. One wave per node, lane =
// feature dim. One coalesced 4B/lane (256B/wave) gather per neighbor.
// ---------------------------------------------------------------------------
__device__ __forceinline__ float wave_sum(float x) {
    #pragma unroll
    for (int off = 32; off > 0; off >>= 1) x += __shfl_xor(x, off);
    return x;
}
__device__ __forceinline__ float wave_max(float x) {
    #pragma unroll
    for (int off = 32; off > 0; off >>= 1) x = fmaxf(x, __shfl_xor(x, off));
    return x;
}

__global__ __launch_bounds__(256) void agg_kernel(
    const float* __restrict__ h,
    const unsigned int* __restrict__ hg,
    const int* __restrict__ offs,
    const int* __restrict__ csr_src, const float* __restrict__ csr_nrm,
    const float* __restrict__ dinv,
    const float* __restrict__ w_gh, const float* __restrict__ b_gh,
    const float* __restrict__ w_gl, const float* __restrict__ b_gl,
    const float* __restrict__ w_gi, const float* __restrict__ b_gi,
    float* __restrict__ out) {
    int v = blockIdx.x * 4 + (threadIdx.x >> 6);
    int lane = threadIdx.x & 63;
    if (v >= N_NODES) return;

    int start = offs[v], end = offs[v + 1];
    float acc_hp = 0.f, acc_lp = 0.f;

    for (int j0 = start; j0 < end; j0 += 64) {
        int m = end - j0; if (m > 64) m = 64;
        int uu = 0; float nn = 0.f;
        if (lane < m) { uu = csr_src[j0 + lane]; nn = csr_nrm[j0 + lane]; }
        #pragma unroll 4
        for (int k = 0; k < m; ++k) {
            int u = __shfl(uu, k);
            float nrm = __shfl(nn, k);
            unsigned int g = hg[(size_t)u * 64 + lane];
            acc_hp = fmaf(nrm, __uint_as_float(g << 16), acc_hp);
            acc_lp = fmaf(nrm, __uint_as_float(g & 0xffff0000u), acc_lp);
        }
    }

    const float* hv = h + (size_t)v * 192;
    float hhp = hv[lane], hlp = hv[64 + lane], hi = hv[128 + lane];
    float dv = dinv[v];
    float Hhp = fmaxf(hhp - (acc_hp + dv * hhp), 0.f);
    float Hlp = fmaxf(acc_lp + dv * hlp, 0.f);
    float Hi  = fmaxf(hi, 0.f);

    float sh = wave_sum(Hhp * w_gh[lane]) + b_gh[0];
    float sl = wave_sum(Hlp * w_gl[lane]) + b_gl[0];
    float si = wave_sum(Hi  * w_gi[lane]) + b_gi[0];

    float o = sh * Hhp + sl * Hlp + si * Hi;
    float mx = wave_max(o);
    float se = wave_sum(expf(o - mx));
    out[(size_t)v * 64 + lane] = o - mx - logf(se);
}

// ---------------------------------------------------------------------------
static inline size_t align256(size_t v) { return (v + 255) & ~(size_t)255; }

extern "C" void kernel_launch(void* const* d_in, const int* in_sizes, int n_in,
                              void* d_out, int out_size, void* d_ws, size_t ws_size,
                              hipStream_t stream) {
    const float* x    = (const float*)d_in[0];
    const void*  ei   = d_in[1];
    const float* Whp  = (const float*)d_in[2];
    const float* bhp  = (const float*)d_in[3];
    const float* Wlp  = (const float*)d_in[4];
    const float* blp  = (const float*)d_in[5];
    const float* Wi   = (const float*)d_in[6];
    const float* bi   = (const float*)d_in[7];
    const float* w_gh = (const float*)d_in[8];
    const float* b_gh = (const float*)d_in[9];
    const float* w_gl = (const float*)d_in[10];
    const float* b_gl = (const float*)d_in[11];
    const float* w_gi = (const float*)d_in[12];
    const float* b_gi = (const float*)d_in[13];
    float* out = (float*)d_out;

    const int N = N_NODES, E = N_EDGES;

    // workspace layout (256B-aligned regions)
    char* base = (char*)d_ws;
    size_t off = 0;
    int* flag = (int*)(base + off);            off = align256(off + sizeof(int));
    size_t deg_off = off;
    int* deg = (int*)(base + off);             off = align256(off + (size_t)N * 4);
    int* offs = (int*)(base + off);            off = align256(off + (size_t)(N + 1) * 4);
    int* cursor = (int*)(base + off);          off = align256(off + (size_t)N * 4);
    float* isq = (float*)(base + off);         off = align256(off + (size_t)N * 4);
    float* dinv = (float*)(base + off);        off = align256(off + (size_t)N * 4);
    int* csr_src = (int*)(base + off);         off = align256(off + (size_t)E * 4);
    float* csr_nrm = (float*)(base + off);     off = align256(off + (size_t)E * 4);
    float* biasAll = (float*)(base + off);     off = align256(off + 192 * 4);
    __hip_bfloat16* Wt = (__hip_bfloat16*)(base + off); off = align256(off + 192 * 256 * 2);
    float* h = (float*)(base + off);           off = align256(off + (size_t)N * 192 * 4);
    unsigned int* hg = (unsigned int*)(base + off); off = align256(off + (size_t)N * 64 * 4);

    // zero flag + deg
    hipMemsetAsync(base, 0, deg_off + (size_t)N * 4, stream);

    detect_dtype_kernel<<<256, 256, 0, stream>>>((const int*)ei, flag, 2 * E);
    degree_kernel<<<2048, 256, 0, stream>>>(ei, flag, deg);
    scan_kernel<<<1, 1024, 0, stream>>>(deg, offs, cursor, isq, dinv);
    fill_kernel<<<2048, 256, 0, stream>>>(ei, flag, cursor, isq, csr_src, csr_nrm);
    prep_w_kernel<<<192, 256, 0, stream>>>(Whp, bhp, Wlp, blp, Wi, bi, Wt, biasAll);
    gemm_kernel<<<(N + 63) / 64, 256, 0, stream>>>(x, Wt, biasAll, h, hg);
    agg_kernel<<<(N + 3) / 4, 256, 0, stream>>>(h, hg, offs, csr_src, csr_nrm, dinv,
                                                w_gh, b_gh, w_gl, b_gl, w_gi, b_gi, out);
}

// Round 3
// 573.106 us; speedup vs baseline: 2.3271x; 1.6821x over previous
//
#include <hip/hip_runtime.h>
#include <hip/hip_bf16.h>

#define N_NODES 100000
#define N_EDGES 3200000
#define IN_DIM  256
#define OUT_DIM 64
#define NB_SCAN ((N_NODES + 255) / 256)   // 391

typedef __attribute__((ext_vector_type(8))) short short8;
typedef __attribute__((ext_vector_type(4))) float float4v;

// ---------------------------------------------------------------------------
// Kernel 1: detect edge_index dtype. int64 (values < 2^31) -> every odd 32-bit
// word is 0. int32 -> odd words are node ids (nonzero w.h.p.). flag=1 -> int32.
// ---------------------------------------------------------------------------
__global__ void detect_dtype_kernel(const int* __restrict__ ei32, int* __restrict__ flag, int nwords) {
    int i = blockIdx.x * blockDim.x + threadIdx.x;
    int stride = blockDim.x * gridDim.x;
    int found = 0;
    for (int w = 2 * i + 1; w < nwords; w += 2 * stride)
        found |= (ei32[w] != 0);
    if (found) atomicOr(flag, 1);
}

__device__ __forceinline__ void load_edge(const void* ei, int e, bool is64, int& s, int& d) {
    if (is64) {
        const long long* e64 = (const long long*)ei;
        s = (int)e64[e];
        d = (int)e64[N_EDGES + e];
    } else {
        const int* e32 = (const int*)ei;
        s = e32[e];
        d = e32[N_EDGES + e];
    }
}

// ---------------------------------------------------------------------------
// Kernel 2: degree count on destination
// ---------------------------------------------------------------------------
__global__ void degree_kernel(const void* __restrict__ ei, const int* __restrict__ flag,
                              int* __restrict__ deg) {
    bool is64 = (*flag == 0);
    int i = blockIdx.x * blockDim.x + threadIdx.x;
    int stride = blockDim.x * gridDim.x;
    for (int e = i; e < N_EDGES; e += stride) {
        int s, d;
        load_edge(ei, e, is64, s, d);
        atomicAdd(&deg[d], 1);
    }
}

// ---------------------------------------------------------------------------
// Kernels 3a/3b/3c: hierarchical exclusive scan of deg -> offs/cursor/isq/dinv
// ---------------------------------------------------------------------------
__global__ __launch_bounds__(256) void scan1_kernel(const int* __restrict__ deg,
                                                    int* __restrict__ bsum) {
    __shared__ int red[256];
    int tid = threadIdx.x;
    int i = blockIdx.x * 256 + tid;
    int v = (i < N_NODES) ? deg[i] : 0;
    red[tid] = v;
    __syncthreads();
    #pragma unroll
    for (int off = 128; off > 0; off >>= 1) {
        if (tid < off) red[tid] += red[tid + off];
        __syncthreads();
    }
    if (tid == 0) bsum[blockIdx.x] = red[0];
}

__global__ __launch_bounds__(512) void scan2_kernel(int* __restrict__ bsum) {
    __shared__ int sh[512];
    int tid = threadIdx.x;
    int v = (tid < NB_SCAN) ? bsum[tid] : 0;
    sh[tid] = v;
    __syncthreads();
    int val = v;
    #pragma unroll
    for (int off = 1; off < 512; off <<= 1) {
        int t = (tid >= off) ? sh[tid - off] : 0;
        __syncthreads();
        val += t;
        sh[tid] = val;
        __syncthreads();
    }
    if (tid < NB_SCAN) bsum[tid] = val - v;   // exclusive block prefix
}

__global__ __launch_bounds__(256) void scan3_kernel(const int* __restrict__ deg,
                                                    const int* __restrict__ bsum,
                                                    int* __restrict__ offs,
                                                    int* __restrict__ cursor,
                                                    float* __restrict__ isq,
                                                    float* __restrict__ dinv) {
    __shared__ int sh[256];
    int tid = threadIdx.x;
    int i = blockIdx.x * 256 + tid;
    int d = (i < N_NODES) ? deg[i] : 0;
    sh[tid] = d;
    __syncthreads();
    int val = d;
    #pragma unroll
    for (int off = 1; off < 256; off <<= 1) {
        int t = (tid >= off) ? sh[tid - off] : 0;
        __syncthreads();
        val += t;
        sh[tid] = val;
        __syncthreads();
    }
    int ex = bsum[blockIdx.x] + val - d;      // exclusive prefix for node i
    if (i < N_NODES) {
        offs[i] = ex;
        cursor[i] = ex;
        float dr = (float)(d + 1);
        isq[i] = rsqrtf(dr);
        dinv[i] = 1.0f / dr;
    }
    if (i == 0) offs[N_NODES] = N_EDGES;      // total degree == E by construction
}

// ---------------------------------------------------------------------------
// Kernel 4: CSR fill — packed 8B record {src, norm} per edge (1 line/scatter)
// ---------------------------------------------------------------------------
__global__ void fill_kernel(const void* __restrict__ ei, const int* __restrict__ flag,
                            int* __restrict__ cursor, const float* __restrict__ isq,
                            unsigned long long* __restrict__ csr) {
    bool is64 = (*flag == 0);
    int i = blockIdx.x * blockDim.x + threadIdx.x;
    int stride = blockDim.x * gridDim.x;
    for (int e = i; e < N_EDGES; e += stride) {
        int s, d;
        load_edge(ei, e, is64, s, d);
        int pos = atomicAdd(&cursor[d], 1);
        float nrm = isq[s] * isq[d];
        csr[pos] = (unsigned long long)(unsigned int)s
                 | ((unsigned long long)__float_as_uint(nrm) << 32);
    }
}

// ---------------------------------------------------------------------------
// Kernel 5: prep weights: Wt[c][k] = bf16(W[k][c]), bias vector biasAll[192].
// ---------------------------------------------------------------------------
__global__ void prep_w_kernel(const float* __restrict__ Whp, const float* __restrict__ bhp,
                              const float* __restrict__ Wlp, const float* __restrict__ blp,
                              const float* __restrict__ Wi,  const float* __restrict__ bi,
                              __hip_bfloat16* __restrict__ Wt, float* __restrict__ biasAll) {
    int c = blockIdx.x;      // 0..191
    int k = threadIdx.x;     // 0..255
    const float* W = (c < 64) ? Whp : (c < 128) ? Wlp : Wi;
    int cl = c & 63;
    Wt[c * 256 + k] = __float2bfloat16(W[k * 64 + cl]);
    if (k == 0) {
        const float* b = (c < 64) ? bhp : (c < 128) ? blp : bi;
        biasAll[c] = b[cl];
    }
}

// ---------------------------------------------------------------------------
// Kernel 6: bf16 MFMA GEMM. Block = 256 threads (4 waves), 64 nodes.
// ---------------------------------------------------------------------------
__global__ __launch_bounds__(256) void gemm_kernel(
    const float* __restrict__ x,
    const __hip_bfloat16* __restrict__ Wt,
    const float* __restrict__ biasAll,
    float* __restrict__ h, unsigned int* __restrict__ hg) {

    __shared__ __align__(16) __hip_bfloat16 xs[64][264];

    const int tid = threadIdx.x;
    const int node0 = blockIdx.x * 64;
    const int w = tid >> 6;
    const int lane = tid & 63;
    const int cl = lane & 15;
    const int kh = lane >> 4;

    // --- B fragments: Wt[col][ks*32 + kh*8 .. +8], col = 16w + 64s + cl ---
    short8 B[3][8];
    #pragma unroll
    for (int s = 0; s < 3; ++s) {
        const __hip_bfloat16* wp = Wt + (16 * w + 64 * s + cl) * 256 + kh * 8;
        #pragma unroll
        for (int ks = 0; ks < 8; ++ks)
            B[s][ks] = *(const short8*)(wp + ks * 32);
    }

    // --- stage x tile (64 x 256 f32 -> bf16 LDS), coalesced 16B/lane ---
    #pragma unroll
    for (int j = 0; j < 16; ++j) {
        int f = j * 1024 + tid * 4;          // flat float index in tile
        int rr = f >> 8, cc = f & 255;
        float4v v = {0.f, 0.f, 0.f, 0.f};
        int node = node0 + rr;
        if (node < N_NODES)
            v = *(const float4v*)(x + (size_t)node * 256 + cc);
        __hip_bfloat16 b0 = __float2bfloat16(v.x), b1 = __float2bfloat16(v.y);
        __hip_bfloat16 b2 = __float2bfloat16(v.z), b3 = __float2bfloat16(v.w);
        unsigned int lo = (unsigned int)*(unsigned short*)&b0 | ((unsigned int)*(unsigned short*)&b1 << 16);
        unsigned int hi = (unsigned int)*(unsigned short*)&b2 | ((unsigned int)*(unsigned short*)&b3 << 16);
        unsigned int* dst = (unsigned int*)&xs[rr][cc];
        dst[0] = lo; dst[1] = hi;
    }
    __syncthreads();

    // --- MFMA main loop: 8 k-steps x (4 row tiles x 3 col slots) ---
    float4v acc[4][3];
    #pragma unroll
    for (int rt = 0; rt < 4; ++rt)
        #pragma unroll
        for (int s = 0; s < 3; ++s)
            acc[rt][s] = (float4v){0.f, 0.f, 0.f, 0.f};

    const char* xbase = (const char*)&xs[0][0];
    #pragma unroll
    for (int ks = 0; ks < 8; ++ks) {
        short8 A[4];
        #pragma unroll
        for (int rt = 0; rt < 4; ++rt)
            A[rt] = *(const short8*)(xbase + (size_t)(rt * 16 + cl) * 528 + ks * 64 + kh * 16);
        #pragma unroll
        for (int rt = 0; rt < 4; ++rt)
            #pragma unroll
            for (int s = 0; s < 3; ++s)
                acc[rt][s] = __builtin_amdgcn_mfma_f32_16x16x32_bf16(A[rt], B[s][ks], acc[rt][s], 0, 0, 0);
    }

    // --- epilogue: bias + store h (f32) + packed bf16x2 gather table ---
    const int c0 = 16 * w + cl;
    const float bias_hp = biasAll[c0];
    const float bias_lp = biasAll[c0 + 64];
    const float bias_i  = biasAll[c0 + 128];

    #pragma unroll
    for (int rt = 0; rt < 4; ++rt) {
        #pragma unroll
        for (int r = 0; r < 4; ++r) {
            int node = node0 + rt * 16 + kh * 4 + r;
            if (node >= N_NODES) continue;
            float vhp = acc[rt][0][r] + bias_hp;
            float vlp = acc[rt][1][r] + bias_lp;
            float vi  = acc[rt][2][r] + bias_i;
            float* hrow = h + (size_t)node * 192;
            hrow[c0]       = vhp;
            hrow[c0 + 64]  = vlp;
            hrow[c0 + 128] = vi;
            __hip_bfloat16 bh = __float2bfloat16(vhp);
            __hip_bfloat16 bl = __float2bfloat16(vlp);
            hg[(size_t)node * 64 + c0] =
                (unsigned int)*(unsigned short*)&bh | ((unsigned int)*(unsigned short*)&bl << 16);
        }
    }
}

// ---------------------------------------------------------------------------
// Kernel 7: fused aggregation + gates + log_softmax. One wave per node, lane =
// feature dim. One coalesced 4B/lane (256B/wave) gather per neighbor.
// ---------------------------------------------------------------------------
__device__ __forceinline__ float wave_sum(float x) {
    #pragma unroll
    for (int off = 32; off > 0; off >>= 1) x += __shfl_xor(x, off);
    return x;
}
__device__ __forceinline__ float wave_max(float x) {
    #pragma unroll
    for (int off = 32; off > 0; off >>= 1) x = fmaxf(x, __shfl_xor(x, off));
    return x;
}

__global__ __launch_bounds__(256) void agg_kernel(
    const float* __restrict__ h,
    const unsigned int* __restrict__ hg,
    const int* __restrict__ offs,
    const unsigned long long* __restrict__ csr,
    const float* __restrict__ dinv,
    const float* __restrict__ w_gh, const float* __restrict__ b_gh,
    const float* __restrict__ w_gl, const float* __restrict__ b_gl,
    const float* __restrict__ w_gi, const float* __restrict__ b_gi,
    float* __restrict__ out) {
    int v = blockIdx.x * 4 + (threadIdx.x >> 6);
    int lane = threadIdx.x & 63;
    if (v >= N_NODES) return;

    int start = offs[v], end = offs[v + 1];
    float acc_hp = 0.f, acc_lp = 0.f;

    for (int j0 = start; j0 < end; j0 += 64) {
        int m = end - j0; if (m > 64) m = 64;
        int uu = 0; float nn = 0.f;
        if (lane < m) {
            unsigned long long pk = csr[j0 + lane];
            uu = (int)(unsigned int)(pk & 0xffffffffu);
            nn = __uint_as_float((unsigned int)(pk >> 32));
        }
        #pragma unroll 4
        for (int k = 0; k < m; ++k) {
            int u = __shfl(uu, k);
            float nrm = __shfl(nn, k);
            unsigned int g = hg[(size_t)u * 64 + lane];
            acc_hp = fmaf(nrm, __uint_as_float(g << 16), acc_hp);
            acc_lp = fmaf(nrm, __uint_as_float(g & 0xffff0000u), acc_lp);
        }
    }

    const float* hv = h + (size_t)v * 192;
    float hhp = hv[lane], hlp = hv[64 + lane], hi = hv[128 + lane];
    float dv = dinv[v];
    float Hhp = fmaxf(hhp - (acc_hp + dv * hhp), 0.f);
    float Hlp = fmaxf(acc_lp + dv * hlp, 0.f);
    float Hi  = fmaxf(hi, 0.f);

    float sh = wave_sum(Hhp * w_gh[lane]) + b_gh[0];
    float sl = wave_sum(Hlp * w_gl[lane]) + b_gl[0];
    float si = wave_sum(Hi  * w_gi[lane]) + b_gi[0];

    float o = sh * Hhp + sl * Hlp + si * Hi;
    float mx = wave_max(o);
    float se = wave_sum(expf(o - mx));
    out[(size_t)v * 64 + lane] = o - mx - logf(se);
}

// ---------------------------------------------------------------------------
static inline size_t align256(size_t v) { return (v + 255) & ~(size_t)255; }

extern "C" void kernel_launch(void* const* d_in, const int* in_sizes, int n_in,
                              void* d_out, int out_size, void* d_ws, size_t ws_size,
                              hipStream_t stream) {
    const float* x    = (const float*)d_in[0];
    const void*  ei   = d_in[1];
    const float* Whp  = (const float*)d_in[2];
    const float* bhp  = (const float*)d_in[3];
    const float* Wlp  = (const float*)d_in[4];
    const float* blp  = (const float*)d_in[5];
    const float* Wi   = (const float*)d_in[6];
    const float* bi   = (const float*)d_in[7];
    const float* w_gh = (const float*)d_in[8];
    const float* b_gh = (const float*)d_in[9];
    const float* w_gl = (const float*)d_in[10];
    const float* b_gl = (const float*)d_in[11];
    const float* w_gi = (const float*)d_in[12];
    const float* b_gi = (const float*)d_in[13];
    float* out = (float*)d_out;

    const int N = N_NODES, E = N_EDGES;

    // workspace layout (256B-aligned regions)
    char* base = (char*)d_ws;
    size_t off = 0;
    int* flag = (int*)(base + off);            off = align256(off + sizeof(int));
    size_t deg_off = off;
    int* deg = (int*)(base + off);             off = align256(off + (size_t)N * 4);
    int* offs = (int*)(base + off);            off = align256(off + (size_t)(N + 1) * 4);
    int* cursor = (int*)(base + off);          off = align256(off + (size_t)N * 4);
    float* isq = (float*)(base + off);         off = align256(off + (size_t)N * 4);
    float* dinv = (float*)(base + off);        off = align256(off + (size_t)N * 4);
    int* bsum = (int*)(base + off);            off = align256(off + (size_t)NB_SCAN * 4);
    unsigned long long* csr = (unsigned long long*)(base + off); off = align256(off + (size_t)E * 8);
    float* biasAll = (float*)(base + off);     off = align256(off + 192 * 4);
    __hip_bfloat16* Wt = (__hip_bfloat16*)(base + off); off = align256(off + 192 * 256 * 2);
    float* h = (float*)(base + off);           off = align256(off + (size_t)N * 192 * 4);
    unsigned int* hg = (unsigned int*)(base + off); off = align256(off + (size_t)N * 64 * 4);

    // zero flag + deg
    hipMemsetAsync(base, 0, deg_off + (size_t)N * 4, stream);

    detect_dtype_kernel<<<256, 256, 0, stream>>>((const int*)ei, flag, 2 * E);
    degree_kernel<<<2048, 256, 0, stream>>>(ei, flag, deg);
    scan1_kernel<<<NB_SCAN, 256, 0, stream>>>(deg, bsum);
    scan2_kernel<<<1, 512, 0, stream>>>(bsum);
    scan3_kernel<<<NB_SCAN, 256, 0, stream>>>(deg, bsum, offs, cursor, isq, dinv);
    fill_kernel<<<2048, 256, 0, stream>>>(ei, flag, cursor, isq, csr);
    prep_w_kernel<<<192, 256, 0, stream>>>(Whp, bhp, Wlp, blp, Wi, bi, Wt, biasAll);
    gemm_kernel<<<(N + 63) / 64, 256, 0, stream>>>(x, Wt, biasAll, h, hg);
    agg_kernel<<<(N + 3) / 4, 256, 0, stream>>>(h, hg, offs, csr, dinv,
                                                w_gh, b_gh, w_gl, b_gl, w_gi, b_gi, out);
}